// Round 4
// baseline (93.717 us; speedup 1.0000x reference)
//
#include <hip/hip_runtime.h>
#include <math.h>

#define T_UTT 50
#define H_DIM 512
#define B_DIM 4096
#define NWAVES 8
#define NT_PW 7    // ceil(T_UTT / NWAVES); waves 0-1 get 7 t's, waves 2-7 get 6

typedef float f32x4 __attribute__((ext_vector_type(4)));

__device__ __forceinline__ float dot8(f32x4 a0, f32x4 a1, f32x4 b0, f32x4 b1) {
    float s = 0.f;
#pragma unroll
    for (int j = 0; j < 4; ++j) s += a0[j] * b0[j];
#pragma unroll
    for (int j = 0; j < 4; ++j) s += a1[j] * b1[j];
    return s;
}

// 512 threads = 8 waves per block, one block per batch row b.
// __launch_bounds__(512, 4): caps VGPR at 128 (u-array 56 + q 8 + acc 8 + temps).
__global__ __launch_bounds__(512, 4) void wseq_attn(const float* __restrict__ Q,
                                                    const float* __restrict__ U,
                                                    float* __restrict__ Out) {
    const int b    = blockIdx.x;
    const int tid  = threadIdx.x;
    const int lane = tid & 63;
    const int wave = tid >> 6;
    const int h0   = lane << 3;   // 8 floats per lane, 64 lanes = 512 = H_DIM

    __shared__ float s_score[T_UTT];
    __shared__ float s_q[H_DIM];
    __shared__ float s_part[NWAVES][H_DIM];

    // ---- query fragment: index via f32x4* (qp+1 == +16 BYTES, not +4) ----
    const f32x4* qp = reinterpret_cast<const f32x4*>(Q + (size_t)b * H_DIM + h0);
    f32x4 q0 = qp[0];
    f32x4 q1 = qp[1];

    // ---- Phase A: issue ALL utterance loads (nontemporal: data is single-use) ----
    f32x4 u0[NT_PW], u1[NT_PW];
#pragma unroll
    for (int i = 0; i < NT_PW; ++i) {
        const int t = wave + NWAVES * i;
        if (t < T_UTT) {
            const f32x4* up =
                reinterpret_cast<const f32x4*>(U + ((size_t)t * B_DIM + b) * H_DIM + h0);
            u0[i] = __builtin_nontemporal_load(up);
            u1[i] = __builtin_nontemporal_load(up + 1);
        }
    }

    // stash q for the fully-parallel epilogue
    if (wave == 0) {
        *reinterpret_cast<f32x4*>(&s_q[h0])     = q0;
        *reinterpret_cast<f32x4*>(&s_q[h0 + 4]) = q1;
    }

    // ---- q norm^2: per-wave butterfly (all lanes get result) ----
    float qn = dot8(q0, q1, q0, q1);
#pragma unroll
    for (int m = 32; m; m >>= 1) qn += __shfl_xor(qn, m, 64);
    const float q_inv = rsqrtf(qn);

    // ---- Phase B: dot + norm^2 butterflies; lane 0 writes the cosine score ----
#pragma unroll
    for (int i = 0; i < NT_PW; ++i) {
        const int t = wave + NWAVES * i;
        if (t < T_UTT) {
            float d = dot8(q0, q1, u0[i], u1[i]);
            float n = dot8(u0[i], u1[i], u0[i], u1[i]);
#pragma unroll
            for (int m = 32; m; m >>= 1) {
                d += __shfl_xor(d, m, 64);
                n += __shfl_xor(n, m, 64);
            }
            if (lane == 0) s_score[t] = d * q_inv * rsqrtf(n);
        }
    }
    __syncthreads();

    // ---- wave-parallel softmax over 51 scores (lane t owns score t) ----
    // lane 50 holds the appended fixed score 1.0; lanes 51-63 hold -inf -> e=0
    float v = (lane < T_UTT) ? s_score[lane]
                             : ((lane == T_UTT) ? 1.0f : -INFINITY);
    float mx = v;
#pragma unroll
    for (int m = 32; m; m >>= 1) mx = fmaxf(mx, __shfl_xor(mx, m, 64));
    float e = __expf(v - mx);          // ONE exp per lane (was ~57 serial)
    float sum = e;
#pragma unroll
    for (int m = 32; m; m >>= 1) sum += __shfl_xor(sum, m, 64);
    const float ew = e * (1.0f / sum); // per-lane softmax weight

    // ---- Phase D: weighted sum from registers; weights via lane broadcast ----
    float acc[8] = {0.f, 0.f, 0.f, 0.f, 0.f, 0.f, 0.f, 0.f};
#pragma unroll
    for (int i = 0; i < NT_PW; ++i) {
        const int t = wave + NWAVES * i;
        if (t < T_UTT) {
            const float w = __shfl(ew, t, 64);   // wave-uniform srcLane
            acc[0] += w * u0[i][0]; acc[1] += w * u0[i][1];
            acc[2] += w * u0[i][2]; acc[3] += w * u0[i][3];
            acc[4] += w * u1[i][0]; acc[5] += w * u1[i][1];
            acc[6] += w * u1[i][2]; acc[7] += w * u1[i][3];
        }
    }
    f32x4* sp = reinterpret_cast<f32x4*>(&s_part[wave][h0]);
    sp[0] = (f32x4){acc[0], acc[1], acc[2], acc[3]};
    sp[1] = (f32x4){acc[4], acc[5], acc[6], acc[7]};
    __syncthreads();

    // ---- epilogue: fully parallel — each of 512 threads owns one h ----
    const float wq = __shfl(ew, T_UTT, 64);   // weight of the query itself
    float o = wq * s_q[tid];
#pragma unroll
    for (int w = 0; w < NWAVES; ++w) o += s_part[w][tid];
    __builtin_nontemporal_store(o, &Out[(size_t)b * H_DIM + tid]);
}

extern "C" void kernel_launch(void* const* d_in, const int* in_sizes, int n_in,
                              void* d_out, int out_size, void* d_ws, size_t ws_size,
                              hipStream_t stream) {
    const float* Q = (const float*)d_in[0];   // [B, H]
    const float* U = (const float*)d_in[1];   // [T, B, H]
    float* Out = (float*)d_out;               // [B, H]
    wseq_attn<<<dim3(B_DIM), dim3(512), 0, stream>>>(Q, U, Out);
}